// Round 13
// baseline (134.349 us; speedup 1.0000x reference)
//
#include <hip/hip_runtime.h>
#include <hip/hip_bf16.h>

// NormalAttention: B=4, N=1600, C=512, heads=8, dh=64. out = softmax(qk^T/8)@k.
// R18: port the R16/R17-proven staging pattern (global_load_lds w=16 +
// issue-STAGE(kt+1)-before-compute(kt) + one barrier/iter) into attn's
// K-loop. attn's qg-paired waves were loading IDENTICAL K chunks from L2
// (32KB/block/kt for 16KB unique = 640MB L2 reads ~ 18.5us floor). Now the
// unique 16KB (k2 8KB + kt2 8KB) is staged ONCE per block into LDS dbuf
// (2x16KB) and shared by all 4 waves via linear ds_read_b128 (base+lane*16,
// conflict-free, bit-identical values to R10's global loads). Register A/B
// buffering dropped (allocator never realized it: VGPR=60 every round).
// red reduce buffer overlays stage LDS after the final loop barrier.
// proj: R17 verbatim (2-phase prefetch, won twice). cvt: R5 verbatim.

typedef __hip_bfloat16 bf16;
typedef __attribute__((ext_vector_type(8))) short short8;
typedef __attribute__((ext_vector_type(4))) short bfx4;
typedef __attribute__((ext_vector_type(4))) float f32x4;

#define NSP 1600
#define CDIM 512
#define DH 64

#define GLD16(g, l)                                                           \
  __builtin_amdgcn_global_load_lds(                                           \
      (const __attribute__((address_space(1))) unsigned int*)(g),             \
      (__attribute__((address_space(3))) unsigned int*)(l), 16, 0, 0)

__device__ __forceinline__ f32x4 mfma32(short8 a, short8 b, f32x4 c) {
  return __builtin_amdgcn_mfma_f32_16x16x32_bf16(a, b, c, 0, 0, 0);
}

#if __has_builtin(__builtin_amdgcn_mfma_f32_16x16x16bf16_1k)
__device__ __forceinline__ f32x4 mfma_k16(bfx4 a, bfx4 b, f32x4 c) {
  return __builtin_amdgcn_mfma_f32_16x16x16bf16_1k(a, b, c, 0, 0, 0);
}
#else
__device__ __forceinline__ f32x4 mfma_k16(bfx4 a, bfx4 b, f32x4 c) {
  short8 a8 = {a.x, a.y, a.z, a.w, 0, 0, 0, 0};
  short8 b8 = {b.x, b.y, b.z, b.w, 0, 0, 0, 0};
  return __builtin_amdgcn_mfma_f32_16x16x32_bf16(a8, b8, c, 0, 0, 0);
}
#endif

__device__ __forceinline__ short8 cvt8(float4 v0, float4 v1) {
  short8 r; bf16* p = (bf16*)&r;
  p[0] = __float2bfloat16(v0.x); p[1] = __float2bfloat16(v0.y);
  p[2] = __float2bfloat16(v0.z); p[3] = __float2bfloat16(v0.w);
  p[4] = __float2bfloat16(v1.x); p[5] = __float2bfloat16(v1.y);
  p[6] = __float2bfloat16(v1.z); p[7] = __float2bfloat16(v1.w);
  return r;
}

// ---------------------------------------------------------------------------
// cvt: x,w -> bf16 (plain); sin/cos -> (d,n) fp32 transpose.  (R5 verbatim)
// ---------------------------------------------------------------------------
extern "C" __global__ __launch_bounds__(256)
void cvt_kernel(const float* __restrict__ x, const float* __restrict__ w,
                const float* __restrict__ sin_t, const float* __restrict__ cos_t,
                bf16* __restrict__ x_bf, bf16* __restrict__ w_bf,
                float* __restrict__ sinT, float* __restrict__ cosT)
{
  __shared__ float t_lds[64][68];
  const int bid = blockIdx.x, tid = threadIdx.x;
  if (bid < 1600) {
    const size_t i = (size_t)bid * 2048 + tid * 8;
    float4 v0 = *(const float4*)(x + i);
    float4 v1 = *(const float4*)(x + i + 4);
    *(short8*)(x_bf + i) = cvt8(v0, v1);
  } else if (bid < 1856) {
    const size_t i = (size_t)(bid - 1600) * 2048 + tid * 8;
    float4 v0 = *(const float4*)(w + i);
    float4 v1 = *(const float4*)(w + i + 4);
    *(short8*)(w_bf + i) = cvt8(v0, v1);
  } else {
    const int t = bid - 1856;
    const float* src = (t < 25) ? sin_t : cos_t;
    float* dst = (t < 25) ? sinT : cosT;
    const int nt = (t < 25) ? t : t - 25;
    const int r = tid >> 2, c = (tid & 3) * 16;
#pragma unroll
    for (int j = 0; j < 4; ++j)
      *(float4*)&t_lds[r][c + j * 4] =
          *(const float4*)(src + (size_t)(nt * 64 + r) * 64 + c + j * 4);
    __syncthreads();
#pragma unroll
    for (int j4 = 0; j4 < 4; ++j4) {
      float4 o;
      o.x = t_lds[c + j4 * 4 + 0][r];
      o.y = t_lds[c + j4 * 4 + 1][r];
      o.z = t_lds[c + j4 * 4 + 2][r];
      o.w = t_lds[c + j4 * 4 + 3][r];
      *(float4*)(dst + (size_t)r * NSP + nt * 64 + c + j4 * 4) = o;
    }
  }
}

// ---------------------------------------------------------------------------
// proj: R17 verbatim. 128x128 tile, BK=64, grid (50,8). global_load_lds w=16
// staging into double-buffered LDS; issue STAGE(kt+1) before compute(kt),
// one __syncthreads per iter. Read-side XOR swizzle; epilogue R5/R7 verbatim.
// ---------------------------------------------------------------------------
extern "C" __global__ __launch_bounds__(256)
void proj_kernel(const bf16* __restrict__ x_bf, const bf16* __restrict__ w_bf,
                 const float* __restrict__ bias, const float* __restrict__ sinT,
                 const float* __restrict__ cosT, bf16* __restrict__ q_ws,
                 bf16* __restrict__ k2_ws, bf16* __restrict__ kt2_ws)
{
  __shared__ __align__(16) char smem[65536];   // buf0: x16K|w16K, buf1: same
  bf16* ep = (bf16*)smem;                      // [128][132] epilogue overlay

  const int tid  = threadIdx.x;
  const int wave = tid >> 6;
  const int lane = tid & 63;
  const int col  = lane & 15;
  const int quad = lane >> 4;
  const int wm = wave >> 1, wo = wave & 1;
  const int m0 = blockIdx.x * 128;
  const int o0 = blockIdx.y * 128;

  f32x4 acc[4][4];
#pragma unroll
  for (int i = 0; i < 4; ++i)
#pragma unroll
    for (int j = 0; j < 4; ++j) acc[i][j] = {0.f, 0.f, 0.f, 0.f};

  const int rl = lane >> 3;
  const int sck = (lane & 7) ^ rl;
  const int c7 = col & 7;

#define STAGEP(B, KT)                                                         \
  {                                                                           \
    char* xd = smem + (B) * 32768 + wave * 4096;                              \
    char* wd = smem + (B) * 32768 + 16384 + wave * 4096;                      \
    _Pragma("unroll")                                                         \
    for (int i = 0; i < 4; ++i) {                                             \
      const int row = wave * 32 + i * 8 + rl;                                 \
      GLD16(x_bf + ((size_t)(m0 + row) << 9) + (KT) * 64 + sck * 8,           \
            xd + i * 1024);                                                   \
      GLD16(w_bf + ((size_t)(o0 + row) << 9) + (KT) * 64 + sck * 8,           \
            wd + i * 1024);                                                   \
    }                                                                         \
  }

  STAGEP(0, 0)
  __syncthreads();   // buf0 ready

#pragma unroll
  for (int kt = 0; kt < 8; ++kt) {
    if (kt < 7) { STAGEP((kt + 1) & 1, kt + 1) }   // in flight under compute
    const char* xls = smem + (kt & 1) * 32768;
    const char* wls = xls + 16384;
#pragma unroll
    for (int half = 0; half < 2; ++half) {
      short8 af[4], bfr[4];
#pragma unroll
      for (int mt = 0; mt < 4; ++mt) {
        const int r = wm * 64 + mt * 16 + col;
        af[mt] = *(const short8*)(xls + r * 128 + (((half * 4 + quad) ^ c7) << 4));
      }
#pragma unroll
      for (int ot = 0; ot < 4; ++ot) {
        const int r = wo * 64 + ot * 16 + col;
        bfr[ot] = *(const short8*)(wls + r * 128 + (((half * 4 + quad) ^ c7) << 4));
      }
#pragma unroll
      for (int mt = 0; mt < 4; ++mt)
#pragma unroll
        for (int ot = 0; ot < 4; ++ot)
          acc[mt][ot] = mfma32(af[mt], bfr[ot], acc[mt][ot]);
    }
    __syncthreads();   // one barrier/iter: drains stage, protects buf reuse
  }

  // ---- epilogue stage 1: theta_shift -> ep[o_local][m_local] (bf16) ----
  const int b_idx = (m0 + wm * 64) / NSP;
  const int n0w   = m0 + wm * 64 - b_idx * NSP;
  const bool isq  = (o0 < 512);
#pragma unroll
  for (int ot = 0; ot < 4; ++ot) {
    const int o_local = wo * 64 + ot * 16 + col;
    const int o_g = o0 + o_local;
    const float bv = bias[o_g];
    const int d = o_g & 63;
#pragma unroll
    for (int mt = 0; mt < 4; ++mt) {
      const int nl = mt * 16 + quad * 4;
      float t[4], rot[4];
#pragma unroll
      for (int r = 0; r < 4; ++r) t[r] = acc[mt][ot][r] + bv;
#pragma unroll
      for (int r = 0; r < 4; ++r) {
        float tp = __shfl_xor(t[r], 1, 64);
        rot[r] = (lane & 1) ? tp : -tp;
      }
      const float4 c4 = *(const float4*)(cosT + (size_t)d * NSP + n0w + nl);
      const float4 s4 = *(const float4*)(sinT + (size_t)d * NSP + n0w + nl);
      float res[4];
      res[0] = t[0] * c4.x + rot[0] * s4.x;
      res[1] = t[1] * c4.y + rot[1] * s4.y;
      res[2] = t[2] * c4.z + rot[2] * s4.z;
      res[3] = t[3] * c4.w + rot[3] * s4.w;
      if (isq) {
#pragma unroll
        for (int r = 0; r < 4; ++r) res[r] *= 0.125f;
      }
      bfx4 pk; bf16* pp = (bf16*)&pk;
#pragma unroll
      for (int r = 0; r < 4; ++r) pp[r] = __float2bfloat16(res[r]);
      *(bfx4*)&ep[o_local * 132 + wm * 64 + nl] = pk;
    }
  }
  __syncthreads();

  // ---- epilogue stage 2: coalesced global stores (R5/R7 verbatim) ----
  if (isq) {   // q_ws (bh,n,d) natural
    const int m_l = tid >> 1, half = tid & 1;
    const int gm = m0 + m_l;
    const int bi = gm / NSP, n = gm - bi * NSP;
    const int h = (o0 >> 6) + half;
    bf16* base = q_ws + ((size_t)(bi * 8 + h) * NSP + n) * 64;
#pragma unroll
    for (int c = 0; c < 8; ++c) {
      short8 v; bf16* vp = (bf16*)&v;
#pragma unroll
      for (int j = 0; j < 8; ++j) vp[j] = ep[(half * 64 + c * 8 + j) * 132 + m_l];
      *(short8*)(base + c * 8) = v;
    }
  } else {
    const int h0 = (o0 - 512) >> 6;   // 0,2,4,6 ; heads h0, h0+1
    // k2_ws: per (bh,ktile) 512 chunks [kh][ti][f][quad][col];
    // chunk = K[key=(2kh+ti)*16+col][d = (f*4+quad)*8 .. +8]
#pragma unroll
    for (int it = 0; it < 8; ++it) {
      const int ci = it * 256 + tid;              // 0..2047
      const int hh = ci >> 10, T = (ci >> 9) & 1, inner = ci & 511;
      const int ccol = inner & 15, cq = (inner >> 4) & 3;
      const int f = (inner >> 6) & 1, ti = (inner >> 7) & 1, kh2 = (inner >> 8) & 1;
      const int gmb = m0 + T * 64;
      const int bi = gmb / NSP, ktile = (gmb - bi * NSP) >> 6;
      const int m_l = T * 64 + (2 * kh2 + ti) * 16 + ccol;
      const int er0 = hh * 64 + (f * 4 + cq) * 8;
      short8 v; bf16* vp = (bf16*)&v;
#pragma unroll
      for (int j = 0; j < 8; ++j) vp[j] = ep[(er0 + j) * 132 + m_l];
      *(short8*)(k2_ws +
          (((size_t)(bi * 8 + h0 + hh) * 25 + ktile) * 512 + inner) * 8) = v;
    }
    // kt2_ws: per (bh,ktile) 512 chunks [kh][dt][quad][col];
    // chunk = kT[d=dt*16+col][packed keys kh*32+quad*4+{0..3}, +16+{0..3}]
#pragma unroll
    for (int it = 0; it < 8; ++it) {
      const int ci = it * 256 + tid;
      const int hh = ci >> 10, T = (ci >> 9) & 1, inner = ci & 511;
      const int ccol = inner & 15, cq = (inner >> 4) & 3;
      const int dt = (inner >> 6) & 3, kh2 = (inner >> 8) & 1;
      const int gmb = m0 + T * 64;
      const int bi = gmb / NSP, ktile = (gmb - bi * NSP) >> 6;
      const bf16* eprow =
          ep + (hh * 64 + dt * 16 + ccol) * 132 + T * 64 + kh2 * 32 + cq * 4;
      short8 v;
      ((bfx4*)&v)[0] = *(const bfx4*)(eprow);
      ((bfx4*)&v)[1] = *(const bfx4*)(eprow + 16);
      *(short8*)(kt2_ws +
          (((size_t)(bi * 8 + h0 + hh) * 25 + ktile) * 512 + inner) * 8) = v;
    }
  }
}

// ---------------------------------------------------------------------------
// attn: R10 wave structure (qg=wave&1 32 qcols, kh=wave>>1 32 keys), but the
// K chunks are staged ONCE per block into LDS dbuf via global_load_lds and
// shared by all 4 waves: per iter {STAGE(kt+1) -> ds_read frags(kt) ->
// COMPUTEF -> barrier}. red overlays stage LDS after the loop.
// ---------------------------------------------------------------------------

#define ASTAGE(B, KT)                                                         \
  {                                                                           \
    const char* gk = (const char*)(k2b  + (size_t)(KT) * 4096);               \
    const char* gt = (const char*)(kt2b + (size_t)(KT) * 4096);               \
    char* dk = smem + (B) * 16384 + wave * 2048;                              \
    _Pragma("unroll")                                                         \
    for (int j = 0; j < 2; ++j) {                                             \
      GLD16(gk + (wave * 2 + j) * 1024 + lane * 16, dk + j * 1024);           \
      GLD16(gt + (wave * 2 + j) * 1024 + lane * 16, dk + 8192 + j * 1024);    \
    }                                                                         \
  }

#define LOADF_L(KF, KTF, CUR)                                                 \
  {                                                                           \
    const char* kl = smem + (CUR) * 16384;                                    \
    _Pragma("unroll")                                                         \
    for (int ti = 0; ti < 2; ++ti)                                            \
      _Pragma("unroll")                                                       \
      for (int f = 0; f < 2; ++f)                                             \
        KF[ti][f] =                                                           \
            *(const short8*)(kl + (((kh * 2 + ti) * 2 + f) * 64 + lane) * 16);\
    _Pragma("unroll")                                                         \
    for (int dt = 0; dt < 4; ++dt)                                            \
      KTF[dt] = *(const short8*)(kl + 8192 + ((kh * 4 + dt) * 64 + lane) * 16);\
  }

#define COMPUTEF(KF, KTF)                                                     \
  {                                                                           \
    f32x4 s[2][2];                                                            \
    _Pragma("unroll")                                                         \
    for (int ti = 0; ti < 2; ++ti)                                            \
      _Pragma("unroll")                                                       \
      for (int ct = 0; ct < 2; ++ct) {                                        \
        f32x4 t = {0.f, 0.f, 0.f, 0.f};                                       \
        t = mfma32(KF[ti][0], qb[ct][0], t);                                  \
        t = mfma32(KF[ti][1], qb[ct][1], t);                                  \
        s[ti][ct] = t;                                                        \
      }                                                                       \
    bfx4 p4[2][2];                                                            \
    _Pragma("unroll")                                                         \
    for (int ti = 0; ti < 2; ++ti)                                            \
      _Pragma("unroll")                                                       \
      for (int ct = 0; ct < 2; ++ct) {                                        \
        _Pragma("unroll")                                                     \
        for (int r = 0; r < 4; ++r) s[ti][ct][r] = __expf(s[ti][ct][r]);      \
        l_part[ct] +=                                                         \
            s[ti][ct][0] + s[ti][ct][1] + s[ti][ct][2] + s[ti][ct][3];        \
        bf16* pp = (bf16*)&p4[ti][ct];                                        \
        _Pragma("unroll")                                                     \
        for (int r = 0; r < 4; ++r) pp[r] = __float2bfloat16(s[ti][ct][r]);   \
      }                                                                       \
    _Pragma("unroll")                                                         \
    for (int dt = 0; dt < 4; ++dt) {                                          \
      bfx4 alo = __builtin_shufflevector(KTF[dt], KTF[dt], 0, 1, 2, 3);       \
      bfx4 ahi = __builtin_shufflevector(KTF[dt], KTF[dt], 4, 5, 6, 7);       \
      _Pragma("unroll")                                                       \
      for (int ct = 0; ct < 2; ++ct) {                                        \
        oacc[dt][ct] = mfma_k16(alo, p4[0][ct], oacc[dt][ct]);                \
        oacc[dt][ct] = mfma_k16(ahi, p4[1][ct], oacc[dt][ct]);                \
      }                                                                       \
    }                                                                         \
  }

extern "C" __global__ __launch_bounds__(256, 2)
void attn_kernel(const bf16* __restrict__ q_ws, const bf16* __restrict__ k2_ws,
                 const bf16* __restrict__ kt2_ws, float* __restrict__ out)
{
  __shared__ __align__(16) char smem[32768];   // stage dbuf; red overlays
  float* redp = (float*)smem;                  // [2][64][36] after the loop

  // XCD swizzle: flat id; id%8 selects XCD (round-robin heuristic) == bh%8,
  // so all 25 qt-blocks of a bh share one XCD's L2. Bijective on 0..799.
  const int id = blockIdx.x;
  const int xr = id & 7, inner = id >> 3;      // inner 0..99
  const int qt = inner % 25;
  const int bh = (inner / 25) * 8 + xr;        // 0..31
  const int b = bh >> 3, h = bh & 7;
  const int tid  = threadIdx.x;
  const int wave = tid >> 6;
  const int lane = tid & 63;
  const int col  = lane & 15;
  const int quad = lane >> 4;
  const int qg = wave & 1, kh = wave >> 1;

  // loop-invariant Q B-fragments (natural layout, one-time strided gather)
  short8 qb[2][2];
#pragma unroll
  for (int ct = 0; ct < 2; ++ct) {
    const bf16* qp =
        q_ws + ((size_t)bh * NSP + qt * 64 + (qg * 2 + ct) * 16 + col) * 64;
    qb[ct][0] = *(const short8*)(qp + quad * 8);
    qb[ct][1] = *(const short8*)(qp + 32 + quad * 8);
  }

  f32x4 oacc[4][2];
#pragma unroll
  for (int i = 0; i < 4; ++i)
#pragma unroll
    for (int j = 0; j < 2; ++j) oacc[i][j] = {0.f, 0.f, 0.f, 0.f};
  float l_part[2] = {0.f, 0.f};

  const bf16* k2b  = k2_ws  + (size_t)bh * 25 * 4096;
  const bf16* kt2b = kt2_ws + (size_t)bh * 25 * 4096;

  ASTAGE(0, 0)
  __syncthreads();   // buf0 ready

  short8 kf[2][2], ktf[4];
#pragma unroll 1
  for (int kt = 0; kt < 25; ++kt) {
    if (kt < 24) { ASTAGE((kt + 1) & 1, kt + 1) }   // in flight under compute
    LOADF_L(kf, ktf, kt & 1)
    COMPUTEF(kf, ktf)
    __syncthreads();   // drains stage(kt+1), protects buf reuse
  }

  // reduce l over quads (this wave's 32 keys)
#pragma unroll
  for (int ct = 0; ct < 2; ++ct) {
    l_part[ct] += __shfl_xor(l_part[ct], 16, 64);
    l_part[ct] += __shfl_xor(l_part[ct], 32, 64);
  }

  // cross-wave (kh) reduce via LDS (red overlays stage buffers; the final
  // loop barrier guarantees all LDS reads of the stage data are done)
  if (wave >= 2) {
    float* dst = redp + ((size_t)(wave - 2) * 64 + lane) * 36;
#pragma unroll
    for (int dt = 0; dt < 4; ++dt)
#pragma unroll
      for (int ct = 0; ct < 2; ++ct)
        *(f32x4*)(dst + (dt * 2 + ct) * 4) = oacc[dt][ct];
    dst[32] = l_part[0]; dst[33] = l_part[1];
  }
  __syncthreads();
  if (wave < 2) {
    const float* srcr = redp + ((size_t)wave * 64 + lane) * 36;
#pragma unroll
    for (int dt = 0; dt < 4; ++dt)
#pragma unroll
      for (int ct = 0; ct < 2; ++ct)
        oacc[dt][ct] += *(const f32x4*)(srcr + (dt * 2 + ct) * 4);
    const float inv0 = 1.f / (l_part[0] + srcr[32]);
    const float inv1 = 1.f / (l_part[1] + srcr[33]);
#pragma unroll
    for (int ct = 0; ct < 2; ++ct) {
      const float inv = ct ? inv1 : inv0;
      const int qrow = qt * 64 + (qg * 2 + ct) * 16 + col;
      float* ob = out + ((size_t)b * NSP + qrow) * CDIM + h * 64;
#pragma unroll
      for (int dt = 0; dt < 4; ++dt) {
        float4 v;
        v.x = oacc[dt][ct][0] * inv; v.y = oacc[dt][ct][1] * inv;
        v.z = oacc[dt][ct][2] * inv; v.w = oacc[dt][ct][3] * inv;
        *(float4*)(ob + dt * 16 + quad * 4) = v;
      }
    }
  }
}

extern "C" void kernel_launch(void* const* d_in, const int* in_sizes, int n_in,
                              void* d_out, int out_size, void* d_ws, size_t ws_size,
                              hipStream_t stream) {
  const float* x     = (const float*)d_in[0];
  const float* sin_t = (const float*)d_in[1];
  const float* cos_t = (const float*)d_in[2];
  const float* w_qkv = (const float*)d_in[3];
  const float* b_qkv = (const float*)d_in[4];
  float* out = (float*)d_out;

  const size_t QK = (size_t)32 * NSP * DH;
  bf16* q_ws   = (bf16*)d_ws;
  bf16* k2_ws  = q_ws + QK;
  bf16* kt2_ws = k2_ws + QK;
  bf16* x_bf   = kt2_ws + QK;
  bf16* w_bf   = x_bf + (size_t)6400 * CDIM;
  float* sinT  = (float*)(w_bf + (size_t)1024 * CDIM);
  float* cosT  = sinT + (size_t)DH * NSP;

  cvt_kernel<<<1906, 256, 0, stream>>>(x, w_qkv, sin_t, cos_t, x_bf, w_bf, sinT, cosT);

  dim3 gproj(50, 8);
  proj_kernel<<<gproj, 256, 0, stream>>>(x_bf, w_bf, b_qkv, sinT, cosT,
                                         q_ws, k2_ws, kt2_ws);

  attn_kernel<<<800, 256, 0, stream>>>(q_ws, k2_ws, kt2_ws, out);
}

// Round 14
// 132.689 us; speedup vs baseline: 1.0125x; 1.0125x over previous
//
#include <hip/hip_runtime.h>
#include <hip/hip_bf16.h>

// NormalAttention: B=4, N=1600, C=512, heads=8, dh=64. out = softmax(qk^T/8)@k.
// R19: revert R18's attn LDS-staging (regressed +4us: LDS round-trip ~13us >
// duplicate-L2 savings ~9us) back to the exact R17-best config (130.5us):
// cvt R5 + proj R17 (2-phase gload_lds prefetch, won twice) + attn R10
// (LDS-free K-loop). One new lever: s_setprio(1) around attn's MFMA clusters
// (T5) -- documented +4-7% on attn with phase-diverse waves (m191), and our
// attn K-loop is barrier-free with ~12 independent waves/CU. Numerics
// untouched; null result would declare attn at its structural floor.

typedef __hip_bfloat16 bf16;
typedef __attribute__((ext_vector_type(8))) short short8;
typedef __attribute__((ext_vector_type(4))) short bfx4;
typedef __attribute__((ext_vector_type(4))) float f32x4;

#define NSP 1600
#define CDIM 512
#define DH 64

#define GLD16(g, l)                                                           \
  __builtin_amdgcn_global_load_lds(                                           \
      (const __attribute__((address_space(1))) unsigned int*)(g),             \
      (__attribute__((address_space(3))) unsigned int*)(l), 16, 0, 0)

__device__ __forceinline__ f32x4 mfma32(short8 a, short8 b, f32x4 c) {
  return __builtin_amdgcn_mfma_f32_16x16x32_bf16(a, b, c, 0, 0, 0);
}

#if __has_builtin(__builtin_amdgcn_mfma_f32_16x16x16bf16_1k)
__device__ __forceinline__ f32x4 mfma_k16(bfx4 a, bfx4 b, f32x4 c) {
  return __builtin_amdgcn_mfma_f32_16x16x16bf16_1k(a, b, c, 0, 0, 0);
}
#else
__device__ __forceinline__ f32x4 mfma_k16(bfx4 a, bfx4 b, f32x4 c) {
  short8 a8 = {a.x, a.y, a.z, a.w, 0, 0, 0, 0};
  short8 b8 = {b.x, b.y, b.z, b.w, 0, 0, 0, 0};
  return __builtin_amdgcn_mfma_f32_16x16x32_bf16(a8, b8, c, 0, 0, 0);
}
#endif

__device__ __forceinline__ short8 cvt8(float4 v0, float4 v1) {
  short8 r; bf16* p = (bf16*)&r;
  p[0] = __float2bfloat16(v0.x); p[1] = __float2bfloat16(v0.y);
  p[2] = __float2bfloat16(v0.z); p[3] = __float2bfloat16(v0.w);
  p[4] = __float2bfloat16(v1.x); p[5] = __float2bfloat16(v1.y);
  p[6] = __float2bfloat16(v1.z); p[7] = __float2bfloat16(v1.w);
  return r;
}

// ---------------------------------------------------------------------------
// cvt: x,w -> bf16 (plain); sin/cos -> (d,n) fp32 transpose.  (R5 verbatim)
// ---------------------------------------------------------------------------
extern "C" __global__ __launch_bounds__(256)
void cvt_kernel(const float* __restrict__ x, const float* __restrict__ w,
                const float* __restrict__ sin_t, const float* __restrict__ cos_t,
                bf16* __restrict__ x_bf, bf16* __restrict__ w_bf,
                float* __restrict__ sinT, float* __restrict__ cosT)
{
  __shared__ float t_lds[64][68];
  const int bid = blockIdx.x, tid = threadIdx.x;
  if (bid < 1600) {
    const size_t i = (size_t)bid * 2048 + tid * 8;
    float4 v0 = *(const float4*)(x + i);
    float4 v1 = *(const float4*)(x + i + 4);
    *(short8*)(x_bf + i) = cvt8(v0, v1);
  } else if (bid < 1856) {
    const size_t i = (size_t)(bid - 1600) * 2048 + tid * 8;
    float4 v0 = *(const float4*)(w + i);
    float4 v1 = *(const float4*)(w + i + 4);
    *(short8*)(w_bf + i) = cvt8(v0, v1);
  } else {
    const int t = bid - 1856;
    const float* src = (t < 25) ? sin_t : cos_t;
    float* dst = (t < 25) ? sinT : cosT;
    const int nt = (t < 25) ? t : t - 25;
    const int r = tid >> 2, c = (tid & 3) * 16;
#pragma unroll
    for (int j = 0; j < 4; ++j)
      *(float4*)&t_lds[r][c + j * 4] =
          *(const float4*)(src + (size_t)(nt * 64 + r) * 64 + c + j * 4);
    __syncthreads();
#pragma unroll
    for (int j4 = 0; j4 < 4; ++j4) {
      float4 o;
      o.x = t_lds[c + j4 * 4 + 0][r];
      o.y = t_lds[c + j4 * 4 + 1][r];
      o.z = t_lds[c + j4 * 4 + 2][r];
      o.w = t_lds[c + j4 * 4 + 3][r];
      *(float4*)(dst + (size_t)r * NSP + nt * 64 + c + j4 * 4) = o;
    }
  }
}

// ---------------------------------------------------------------------------
// proj: R17 verbatim. 128x128 tile, BK=64, grid (50,8). global_load_lds w=16
// staging into double-buffered LDS; issue STAGE(kt+1) before compute(kt),
// one __syncthreads per iter. Read-side XOR swizzle; epilogue R5/R7 verbatim.
// ---------------------------------------------------------------------------
extern "C" __global__ __launch_bounds__(256)
void proj_kernel(const bf16* __restrict__ x_bf, const bf16* __restrict__ w_bf,
                 const float* __restrict__ bias, const float* __restrict__ sinT,
                 const float* __restrict__ cosT, bf16* __restrict__ q_ws,
                 bf16* __restrict__ k2_ws, bf16* __restrict__ kt2_ws)
{
  __shared__ __align__(16) char smem[65536];   // buf0: x16K|w16K, buf1: same
  bf16* ep = (bf16*)smem;                      // [128][132] epilogue overlay

  const int tid  = threadIdx.x;
  const int wave = tid >> 6;
  const int lane = tid & 63;
  const int col  = lane & 15;
  const int quad = lane >> 4;
  const int wm = wave >> 1, wo = wave & 1;
  const int m0 = blockIdx.x * 128;
  const int o0 = blockIdx.y * 128;

  f32x4 acc[4][4];
#pragma unroll
  for (int i = 0; i < 4; ++i)
#pragma unroll
    for (int j = 0; j < 4; ++j) acc[i][j] = {0.f, 0.f, 0.f, 0.f};

  const int rl = lane >> 3;
  const int sck = (lane & 7) ^ rl;
  const int c7 = col & 7;

#define STAGEP(B, KT)                                                         \
  {                                                                           \
    char* xd = smem + (B) * 32768 + wave * 4096;                              \
    char* wd = smem + (B) * 32768 + 16384 + wave * 4096;                      \
    _Pragma("unroll")                                                         \
    for (int i = 0; i < 4; ++i) {                                             \
      const int row = wave * 32 + i * 8 + rl;                                 \
      GLD16(x_bf + ((size_t)(m0 + row) << 9) + (KT) * 64 + sck * 8,           \
            xd + i * 1024);                                                   \
      GLD16(w_bf + ((size_t)(o0 + row) << 9) + (KT) * 64 + sck * 8,           \
            wd + i * 1024);                                                   \
    }                                                                         \
  }

  STAGEP(0, 0)
  __syncthreads();   // buf0 ready

#pragma unroll
  for (int kt = 0; kt < 8; ++kt) {
    if (kt < 7) { STAGEP((kt + 1) & 1, kt + 1) }   // in flight under compute
    const char* xls = smem + (kt & 1) * 32768;
    const char* wls = xls + 16384;
#pragma unroll
    for (int half = 0; half < 2; ++half) {
      short8 af[4], bfr[4];
#pragma unroll
      for (int mt = 0; mt < 4; ++mt) {
        const int r = wm * 64 + mt * 16 + col;
        af[mt] = *(const short8*)(xls + r * 128 + (((half * 4 + quad) ^ c7) << 4));
      }
#pragma unroll
      for (int ot = 0; ot < 4; ++ot) {
        const int r = wo * 64 + ot * 16 + col;
        bfr[ot] = *(const short8*)(wls + r * 128 + (((half * 4 + quad) ^ c7) << 4));
      }
#pragma unroll
      for (int mt = 0; mt < 4; ++mt)
#pragma unroll
        for (int ot = 0; ot < 4; ++ot)
          acc[mt][ot] = mfma32(af[mt], bfr[ot], acc[mt][ot]);
    }
    __syncthreads();   // one barrier/iter: drains stage, protects buf reuse
  }

  // ---- epilogue stage 1: theta_shift -> ep[o_local][m_local] (bf16) ----
  const int b_idx = (m0 + wm * 64) / NSP;
  const int n0w   = m0 + wm * 64 - b_idx * NSP;
  const bool isq  = (o0 < 512);
#pragma unroll
  for (int ot = 0; ot < 4; ++ot) {
    const int o_local = wo * 64 + ot * 16 + col;
    const int o_g = o0 + o_local;
    const float bv = bias[o_g];
    const int d = o_g & 63;
#pragma unroll
    for (int mt = 0; mt < 4; ++mt) {
      const int nl = mt * 16 + quad * 4;
      float t[4], rot[4];
#pragma unroll
      for (int r = 0; r < 4; ++r) t[r] = acc[mt][ot][r] + bv;
#pragma unroll
      for (int r = 0; r < 4; ++r) {
        float tp = __shfl_xor(t[r], 1, 64);
        rot[r] = (lane & 1) ? tp : -tp;
      }
      const float4 c4 = *(const float4*)(cosT + (size_t)d * NSP + n0w + nl);
      const float4 s4 = *(const float4*)(sinT + (size_t)d * NSP + n0w + nl);
      float res[4];
      res[0] = t[0] * c4.x + rot[0] * s4.x;
      res[1] = t[1] * c4.y + rot[1] * s4.y;
      res[2] = t[2] * c4.z + rot[2] * s4.z;
      res[3] = t[3] * c4.w + rot[3] * s4.w;
      if (isq) {
#pragma unroll
        for (int r = 0; r < 4; ++r) res[r] *= 0.125f;
      }
      bfx4 pk; bf16* pp = (bf16*)&pk;
#pragma unroll
      for (int r = 0; r < 4; ++r) pp[r] = __float2bfloat16(res[r]);
      *(bfx4*)&ep[o_local * 132 + wm * 64 + nl] = pk;
    }
  }
  __syncthreads();

  // ---- epilogue stage 2: coalesced global stores (R5/R7 verbatim) ----
  if (isq) {   // q_ws (bh,n,d) natural
    const int m_l = tid >> 1, half = tid & 1;
    const int gm = m0 + m_l;
    const int bi = gm / NSP, n = gm - bi * NSP;
    const int h = (o0 >> 6) + half;
    bf16* base = q_ws + ((size_t)(bi * 8 + h) * NSP + n) * 64;
#pragma unroll
    for (int c = 0; c < 8; ++c) {
      short8 v; bf16* vp = (bf16*)&v;
#pragma unroll
      for (int j = 0; j < 8; ++j) vp[j] = ep[(half * 64 + c * 8 + j) * 132 + m_l];
      *(short8*)(base + c * 8) = v;
    }
  } else {
    const int h0 = (o0 - 512) >> 6;   // 0,2,4,6 ; heads h0, h0+1
    // k2_ws: per (bh,ktile) 512 chunks [kh][ti][f][quad][col];
    // chunk = K[key=(2kh+ti)*16+col][d = (f*4+quad)*8 .. +8]
#pragma unroll
    for (int it = 0; it < 8; ++it) {
      const int ci = it * 256 + tid;              // 0..2047
      const int hh = ci >> 10, T = (ci >> 9) & 1, inner = ci & 511;
      const int ccol = inner & 15, cq = (inner >> 4) & 3;
      const int f = (inner >> 6) & 1, ti = (inner >> 7) & 1, kh2 = (inner >> 8) & 1;
      const int gmb = m0 + T * 64;
      const int bi = gmb / NSP, ktile = (gmb - bi * NSP) >> 6;
      const int m_l = T * 64 + (2 * kh2 + ti) * 16 + ccol;
      const int er0 = hh * 64 + (f * 4 + cq) * 8;
      short8 v; bf16* vp = (bf16*)&v;
#pragma unroll
      for (int j = 0; j < 8; ++j) vp[j] = ep[(er0 + j) * 132 + m_l];
      *(short8*)(k2_ws +
          (((size_t)(bi * 8 + h0 + hh) * 25 + ktile) * 512 + inner) * 8) = v;
    }
    // kt2_ws: per (bh,ktile) 512 chunks [kh][dt][quad][col];
    // chunk = kT[d=dt*16+col][packed keys kh*32+quad*4+{0..3}, +16+{0..3}]
#pragma unroll
    for (int it = 0; it < 8; ++it) {
      const int ci = it * 256 + tid;
      const int hh = ci >> 10, T = (ci >> 9) & 1, inner = ci & 511;
      const int ccol = inner & 15, cq = (inner >> 4) & 3;
      const int dt = (inner >> 6) & 3, kh2 = (inner >> 8) & 1;
      const int gmb = m0 + T * 64;
      const int bi = gmb / NSP, ktile = (gmb - bi * NSP) >> 6;
      const bf16* eprow =
          ep + (hh * 64 + dt * 16 + ccol) * 132 + T * 64 + kh2 * 32 + cq * 4;
      short8 v;
      ((bfx4*)&v)[0] = *(const bfx4*)(eprow);
      ((bfx4*)&v)[1] = *(const bfx4*)(eprow + 16);
      *(short8*)(kt2_ws +
          (((size_t)(bi * 8 + h0 + hh) * 25 + ktile) * 512 + inner) * 8) = v;
    }
  }
}

// ---------------------------------------------------------------------------
// attn: R10 verbatim structure (LDS-free K-loop, 4 waves: qg=wave&1 32 qcols,
// kh=wave>>1 32 keys; XCD-swizzled flat grid 800; register double-buffer;
// launch_bounds(256,2)) + s_setprio(1) around the two MFMA clusters (T5:
// +4-7% on phase-diverse attn waves, m191; our K-loop is barrier-free).
// ---------------------------------------------------------------------------

#define LOADF(KF, KTF, KT)                                                    \
  {                                                                           \
    const bf16* kc_  = k2b  + (KT) * 4096;                                    \
    const bf16* kc2_ = kt2b + (KT) * 4096;                                    \
    _Pragma("unroll")                                                         \
    for (int ti = 0; ti < 2; ++ti)                                            \
      _Pragma("unroll")                                                       \
      for (int f = 0; f < 2; ++f)                                             \
        KF[ti][f] =                                                           \
            *(const short8*)(kc_ + (((kh * 2 + ti) * 2 + f) * 64 + lane) * 8);\
    _Pragma("unroll")                                                         \
    for (int dt = 0; dt < 4; ++dt)                                            \
      KTF[dt] = *(const short8*)(kc2_ + ((kh * 4 + dt) * 64 + lane) * 8);     \
  }

#define COMPUTEF(KF, KTF)                                                     \
  {                                                                           \
    f32x4 s[2][2];                                                            \
    __builtin_amdgcn_s_setprio(1);                                            \
    _Pragma("unroll")                                                         \
    for (int ti = 0; ti < 2; ++ti)                                            \
      _Pragma("unroll")                                                       \
      for (int ct = 0; ct < 2; ++ct) {                                        \
        f32x4 t = {0.f, 0.f, 0.f, 0.f};                                       \
        t = mfma32(KF[ti][0], qb[ct][0], t);                                  \
        t = mfma32(KF[ti][1], qb[ct][1], t);                                  \
        s[ti][ct] = t;                                                        \
      }                                                                       \
    __builtin_amdgcn_s_setprio(0);                                            \
    bfx4 p4[2][2];                                                            \
    _Pragma("unroll")                                                         \
    for (int ti = 0; ti < 2; ++ti)                                            \
      _Pragma("unroll")                                                       \
      for (int ct = 0; ct < 2; ++ct) {                                        \
        _Pragma("unroll")                                                     \
        for (int r = 0; r < 4; ++r) s[ti][ct][r] = __expf(s[ti][ct][r]);      \
        l_part[ct] +=                                                         \
            s[ti][ct][0] + s[ti][ct][1] + s[ti][ct][2] + s[ti][ct][3];        \
        bf16* pp = (bf16*)&p4[ti][ct];                                        \
        _Pragma("unroll")                                                     \
        for (int r = 0; r < 4; ++r) pp[r] = __float2bfloat16(s[ti][ct][r]);   \
      }                                                                       \
    __builtin_amdgcn_s_setprio(1);                                            \
    _Pragma("unroll")                                                         \
    for (int dt = 0; dt < 4; ++dt) {                                          \
      bfx4 alo = __builtin_shufflevector(KTF[dt], KTF[dt], 0, 1, 2, 3);       \
      bfx4 ahi = __builtin_shufflevector(KTF[dt], KTF[dt], 4, 5, 6, 7);       \
      _Pragma("unroll")                                                       \
      for (int ct = 0; ct < 2; ++ct) {                                        \
        oacc[dt][ct] = mfma_k16(alo, p4[0][ct], oacc[dt][ct]);                \
        oacc[dt][ct] = mfma_k16(ahi, p4[1][ct], oacc[dt][ct]);                \
      }                                                                       \
    }                                                                         \
    __builtin_amdgcn_s_setprio(0);                                            \
  }

extern "C" __global__ __launch_bounds__(256, 2)
void attn_kernel(const bf16* __restrict__ q_ws, const bf16* __restrict__ k2_ws,
                 const bf16* __restrict__ kt2_ws, float* __restrict__ out)
{
  __shared__ float red[2][64][36];

  // XCD swizzle: flat id; id%8 selects XCD (round-robin heuristic) == bh%8,
  // so all 25 qt-blocks of a bh share one XCD's L2. Bijective on 0..799.
  const int id = blockIdx.x;
  const int xr = id & 7, inner = id >> 3;      // inner 0..99
  const int qt = inner % 25;
  const int bh = (inner / 25) * 8 + xr;        // 0..31
  const int b = bh >> 3, h = bh & 7;
  const int tid  = threadIdx.x;
  const int wave = tid >> 6;
  const int lane = tid & 63;
  const int col  = lane & 15;
  const int quad = lane >> 4;
  const int qg = wave & 1, kh = wave >> 1;

  // loop-invariant Q B-fragments (natural layout, one-time strided gather)
  short8 qb[2][2];
#pragma unroll
  for (int ct = 0; ct < 2; ++ct) {
    const bf16* qp =
        q_ws + ((size_t)bh * NSP + qt * 64 + (qg * 2 + ct) * 16 + col) * 64;
    qb[ct][0] = *(const short8*)(qp + quad * 8);
    qb[ct][1] = *(const short8*)(qp + 32 + quad * 8);
  }

  f32x4 oacc[4][2];
#pragma unroll
  for (int i = 0; i < 4; ++i)
#pragma unroll
    for (int j = 0; j < 2; ++j) oacc[i][j] = {0.f, 0.f, 0.f, 0.f};
  float l_part[2] = {0.f, 0.f};

  const bf16* k2b  = k2_ws  + (size_t)bh * 25 * 4096;
  const bf16* kt2b = kt2_ws + (size_t)bh * 25 * 4096;

  // register double-buffer: prefetch kt+1 while computing kt
  short8 kfA[2][2], ktfA[4], kfB[2][2], ktfB[4];
  LOADF(kfA, ktfA, 0)
#pragma unroll 1
  for (int i = 0; i < 12; ++i) {
    LOADF(kfB, ktfB, 2 * i + 1)
    COMPUTEF(kfA, ktfA)
    LOADF(kfA, ktfA, 2 * i + 2)
    COMPUTEF(kfB, ktfB)
  }
  COMPUTEF(kfA, ktfA)

  // reduce l over quads (this wave's 32 keys)
#pragma unroll
  for (int ct = 0; ct < 2; ++ct) {
    l_part[ct] += __shfl_xor(l_part[ct], 16, 64);
    l_part[ct] += __shfl_xor(l_part[ct], 32, 64);
  }

  // cross-wave (kh) reduce via LDS
  if (wave >= 2) {
    float* dst = &red[wave - 2][lane][0];
#pragma unroll
    for (int dt = 0; dt < 4; ++dt)
#pragma unroll
      for (int ct = 0; ct < 2; ++ct)
        *(f32x4*)(dst + (dt * 2 + ct) * 4) = oacc[dt][ct];
    dst[32] = l_part[0]; dst[33] = l_part[1];
  }
  __syncthreads();
  if (wave < 2) {
    const float* srcr = &red[wave][lane][0];
#pragma unroll
    for (int dt = 0; dt < 4; ++dt)
#pragma unroll
      for (int ct = 0; ct < 2; ++ct)
        oacc[dt][ct] += *(const f32x4*)(srcr + (dt * 2 + ct) * 4);
    const float inv0 = 1.f / (l_part[0] + srcr[32]);
    const float inv1 = 1.f / (l_part[1] + srcr[33]);
#pragma unroll
    for (int ct = 0; ct < 2; ++ct) {
      const float inv = ct ? inv1 : inv0;
      const int qrow = qt * 64 + (qg * 2 + ct) * 16 + col;
      float* ob = out + ((size_t)b * NSP + qrow) * CDIM + h * 64;
#pragma unroll
      for (int dt = 0; dt < 4; ++dt) {
        float4 v;
        v.x = oacc[dt][ct][0] * inv; v.y = oacc[dt][ct][1] * inv;
        v.z = oacc[dt][ct][2] * inv; v.w = oacc[dt][ct][3] * inv;
        *(float4*)(ob + dt * 16 + quad * 4) = v;
      }
    }
  }
}

extern "C" void kernel_launch(void* const* d_in, const int* in_sizes, int n_in,
                              void* d_out, int out_size, void* d_ws, size_t ws_size,
                              hipStream_t stream) {
  const float* x     = (const float*)d_in[0];
  const float* sin_t = (const float*)d_in[1];
  const float* cos_t = (const float*)d_in[2];
  const float* w_qkv = (const float*)d_in[3];
  const float* b_qkv = (const float*)d_in[4];
  float* out = (float*)d_out;

  const size_t QK = (size_t)32 * NSP * DH;
  bf16* q_ws   = (bf16*)d_ws;
  bf16* k2_ws  = q_ws + QK;
  bf16* kt2_ws = k2_ws + QK;
  bf16* x_bf   = kt2_ws + QK;
  bf16* w_bf   = x_bf + (size_t)6400 * CDIM;
  float* sinT  = (float*)(w_bf + (size_t)1024 * CDIM);
  float* cosT  = sinT + (size_t)DH * NSP;

  cvt_kernel<<<1906, 256, 0, stream>>>(x, w_qkv, sin_t, cos_t, x_bf, w_bf, sinT, cosT);

  dim3 gproj(50, 8);
  proj_kernel<<<gproj, 256, 0, stream>>>(x_bf, w_bf, b_qkv, sinT, cosT,
                                         q_ws, k2_ws, kt2_ws);

  attn_kernel<<<800, 256, 0, stream>>>(q_ws, k2_ws, kt2_ws, out);
}

// Round 15
// 131.270 us; speedup vs baseline: 1.0235x; 1.0108x over previous
//
#include <hip/hip_runtime.h>
#include <hip/hip_bf16.h>

// NormalAttention: B=4, N=1600, C=512, heads=8, dh=64. out = softmax(qk^T/8)@k.
// R20: R17-best config (130.5us) with setprio removed (R19: neutral/-2us),
// plus the REAL fix for attn's never-materialized register double-buffer:
// attn VGPR=60 in every profile => the scheduler SINKS the B-buffer loads to
// just before use (pressure heuristic), degenerating the 2-deep pipeline to
// a serial chain -- all prior "pipelining is null" results measured a
// pipeline that didn't exist in the emitted code. Fix: sched_barrier(0)
// after each LOADF pins load issue before the MFMA cluster at compile time;
// compiler still auto-inserts correct waitcnts (no inline-asm waitcnt =>
// no rule-#18 hazard). launch_bounds(256) plain so the live buffers
// (~110-150 VGPR expected) aren't squeezed by the 128 cap.
// Falsifiable: VGPR must rise; if VGPR rises and dur doesn't move, the
// load-latency theory is cleanly dead and attn is at its floor.
// proj: R17 verbatim (gload_lds dbuf 2-phase, won twice). cvt: R5 verbatim.

typedef __hip_bfloat16 bf16;
typedef __attribute__((ext_vector_type(8))) short short8;
typedef __attribute__((ext_vector_type(4))) short bfx4;
typedef __attribute__((ext_vector_type(4))) float f32x4;

#define NSP 1600
#define CDIM 512
#define DH 64

#define GLD16(g, l)                                                           \
  __builtin_amdgcn_global_load_lds(                                           \
      (const __attribute__((address_space(1))) unsigned int*)(g),             \
      (__attribute__((address_space(3))) unsigned int*)(l), 16, 0, 0)

__device__ __forceinline__ f32x4 mfma32(short8 a, short8 b, f32x4 c) {
  return __builtin_amdgcn_mfma_f32_16x16x32_bf16(a, b, c, 0, 0, 0);
}

#if __has_builtin(__builtin_amdgcn_mfma_f32_16x16x16bf16_1k)
__device__ __forceinline__ f32x4 mfma_k16(bfx4 a, bfx4 b, f32x4 c) {
  return __builtin_amdgcn_mfma_f32_16x16x16bf16_1k(a, b, c, 0, 0, 0);
}
#else
__device__ __forceinline__ f32x4 mfma_k16(bfx4 a, bfx4 b, f32x4 c) {
  short8 a8 = {a.x, a.y, a.z, a.w, 0, 0, 0, 0};
  short8 b8 = {b.x, b.y, b.z, b.w, 0, 0, 0, 0};
  return __builtin_amdgcn_mfma_f32_16x16x32_bf16(a8, b8, c, 0, 0, 0);
}
#endif

__device__ __forceinline__ short8 cvt8(float4 v0, float4 v1) {
  short8 r; bf16* p = (bf16*)&r;
  p[0] = __float2bfloat16(v0.x); p[1] = __float2bfloat16(v0.y);
  p[2] = __float2bfloat16(v0.z); p[3] = __float2bfloat16(v0.w);
  p[4] = __float2bfloat16(v1.x); p[5] = __float2bfloat16(v1.y);
  p[6] = __float2bfloat16(v1.z); p[7] = __float2bfloat16(v1.w);
  return r;
}

// ---------------------------------------------------------------------------
// cvt: x,w -> bf16 (plain); sin/cos -> (d,n) fp32 transpose.  (R5 verbatim)
// ---------------------------------------------------------------------------
extern "C" __global__ __launch_bounds__(256)
void cvt_kernel(const float* __restrict__ x, const float* __restrict__ w,
                const float* __restrict__ sin_t, const float* __restrict__ cos_t,
                bf16* __restrict__ x_bf, bf16* __restrict__ w_bf,
                float* __restrict__ sinT, float* __restrict__ cosT)
{
  __shared__ float t_lds[64][68];
  const int bid = blockIdx.x, tid = threadIdx.x;
  if (bid < 1600) {
    const size_t i = (size_t)bid * 2048 + tid * 8;
    float4 v0 = *(const float4*)(x + i);
    float4 v1 = *(const float4*)(x + i + 4);
    *(short8*)(x_bf + i) = cvt8(v0, v1);
  } else if (bid < 1856) {
    const size_t i = (size_t)(bid - 1600) * 2048 + tid * 8;
    float4 v0 = *(const float4*)(w + i);
    float4 v1 = *(const float4*)(w + i + 4);
    *(short8*)(w_bf + i) = cvt8(v0, v1);
  } else {
    const int t = bid - 1856;
    const float* src = (t < 25) ? sin_t : cos_t;
    float* dst = (t < 25) ? sinT : cosT;
    const int nt = (t < 25) ? t : t - 25;
    const int r = tid >> 2, c = (tid & 3) * 16;
#pragma unroll
    for (int j = 0; j < 4; ++j)
      *(float4*)&t_lds[r][c + j * 4] =
          *(const float4*)(src + (size_t)(nt * 64 + r) * 64 + c + j * 4);
    __syncthreads();
#pragma unroll
    for (int j4 = 0; j4 < 4; ++j4) {
      float4 o;
      o.x = t_lds[c + j4 * 4 + 0][r];
      o.y = t_lds[c + j4 * 4 + 1][r];
      o.z = t_lds[c + j4 * 4 + 2][r];
      o.w = t_lds[c + j4 * 4 + 3][r];
      *(float4*)(dst + (size_t)r * NSP + nt * 64 + c + j4 * 4) = o;
    }
  }
}

// ---------------------------------------------------------------------------
// proj: R17 verbatim. 128x128 tile, BK=64, grid (50,8). global_load_lds w=16
// staging into double-buffered LDS; issue STAGE(kt+1) before compute(kt),
// one __syncthreads per iter. Read-side XOR swizzle; epilogue R5/R7 verbatim.
// ---------------------------------------------------------------------------
extern "C" __global__ __launch_bounds__(256)
void proj_kernel(const bf16* __restrict__ x_bf, const bf16* __restrict__ w_bf,
                 const float* __restrict__ bias, const float* __restrict__ sinT,
                 const float* __restrict__ cosT, bf16* __restrict__ q_ws,
                 bf16* __restrict__ k2_ws, bf16* __restrict__ kt2_ws)
{
  __shared__ __align__(16) char smem[65536];   // buf0: x16K|w16K, buf1: same
  bf16* ep = (bf16*)smem;                      // [128][132] epilogue overlay

  const int tid  = threadIdx.x;
  const int wave = tid >> 6;
  const int lane = tid & 63;
  const int col  = lane & 15;
  const int quad = lane >> 4;
  const int wm = wave >> 1, wo = wave & 1;
  const int m0 = blockIdx.x * 128;
  const int o0 = blockIdx.y * 128;

  f32x4 acc[4][4];
#pragma unroll
  for (int i = 0; i < 4; ++i)
#pragma unroll
    for (int j = 0; j < 4; ++j) acc[i][j] = {0.f, 0.f, 0.f, 0.f};

  const int rl = lane >> 3;
  const int sck = (lane & 7) ^ rl;
  const int c7 = col & 7;

#define STAGEP(B, KT)                                                         \
  {                                                                           \
    char* xd = smem + (B) * 32768 + wave * 4096;                              \
    char* wd = smem + (B) * 32768 + 16384 + wave * 4096;                      \
    _Pragma("unroll")                                                         \
    for (int i = 0; i < 4; ++i) {                                             \
      const int row = wave * 32 + i * 8 + rl;                                 \
      GLD16(x_bf + ((size_t)(m0 + row) << 9) + (KT) * 64 + sck * 8,           \
            xd + i * 1024);                                                   \
      GLD16(w_bf + ((size_t)(o0 + row) << 9) + (KT) * 64 + sck * 8,           \
            wd + i * 1024);                                                   \
    }                                                                         \
  }

  STAGEP(0, 0)
  __syncthreads();   // buf0 ready

#pragma unroll
  for (int kt = 0; kt < 8; ++kt) {
    if (kt < 7) { STAGEP((kt + 1) & 1, kt + 1) }   // in flight under compute
    const char* xls = smem + (kt & 1) * 32768;
    const char* wls = xls + 16384;
#pragma unroll
    for (int half = 0; half < 2; ++half) {
      short8 af[4], bfr[4];
#pragma unroll
      for (int mt = 0; mt < 4; ++mt) {
        const int r = wm * 64 + mt * 16 + col;
        af[mt] = *(const short8*)(xls + r * 128 + (((half * 4 + quad) ^ c7) << 4));
      }
#pragma unroll
      for (int ot = 0; ot < 4; ++ot) {
        const int r = wo * 64 + ot * 16 + col;
        bfr[ot] = *(const short8*)(wls + r * 128 + (((half * 4 + quad) ^ c7) << 4));
      }
#pragma unroll
      for (int mt = 0; mt < 4; ++mt)
#pragma unroll
        for (int ot = 0; ot < 4; ++ot)
          acc[mt][ot] = mfma32(af[mt], bfr[ot], acc[mt][ot]);
    }
    __syncthreads();   // one barrier/iter: drains stage, protects buf reuse
  }

  // ---- epilogue stage 1: theta_shift -> ep[o_local][m_local] (bf16) ----
  const int b_idx = (m0 + wm * 64) / NSP;
  const int n0w   = m0 + wm * 64 - b_idx * NSP;
  const bool isq  = (o0 < 512);
#pragma unroll
  for (int ot = 0; ot < 4; ++ot) {
    const int o_local = wo * 64 + ot * 16 + col;
    const int o_g = o0 + o_local;
    const float bv = bias[o_g];
    const int d = o_g & 63;
#pragma unroll
    for (int mt = 0; mt < 4; ++mt) {
      const int nl = mt * 16 + quad * 4;
      float t[4], rot[4];
#pragma unroll
      for (int r = 0; r < 4; ++r) t[r] = acc[mt][ot][r] + bv;
#pragma unroll
      for (int r = 0; r < 4; ++r) {
        float tp = __shfl_xor(t[r], 1, 64);
        rot[r] = (lane & 1) ? tp : -tp;
      }
      const float4 c4 = *(const float4*)(cosT + (size_t)d * NSP + n0w + nl);
      const float4 s4 = *(const float4*)(sinT + (size_t)d * NSP + n0w + nl);
      float res[4];
      res[0] = t[0] * c4.x + rot[0] * s4.x;
      res[1] = t[1] * c4.y + rot[1] * s4.y;
      res[2] = t[2] * c4.z + rot[2] * s4.z;
      res[3] = t[3] * c4.w + rot[3] * s4.w;
      if (isq) {
#pragma unroll
        for (int r = 0; r < 4; ++r) res[r] *= 0.125f;
      }
      bfx4 pk; bf16* pp = (bf16*)&pk;
#pragma unroll
      for (int r = 0; r < 4; ++r) pp[r] = __float2bfloat16(res[r]);
      *(bfx4*)&ep[o_local * 132 + wm * 64 + nl] = pk;
    }
  }
  __syncthreads();

  // ---- epilogue stage 2: coalesced global stores (R5/R7 verbatim) ----
  if (isq) {   // q_ws (bh,n,d) natural
    const int m_l = tid >> 1, half = tid & 1;
    const int gm = m0 + m_l;
    const int bi = gm / NSP, n = gm - bi * NSP;
    const int h = (o0 >> 6) + half;
    bf16* base = q_ws + ((size_t)(bi * 8 + h) * NSP + n) * 64;
#pragma unroll
    for (int c = 0; c < 8; ++c) {
      short8 v; bf16* vp = (bf16*)&v;
#pragma unroll
      for (int j = 0; j < 8; ++j) vp[j] = ep[(half * 64 + c * 8 + j) * 132 + m_l];
      *(short8*)(base + c * 8) = v;
    }
  } else {
    const int h0 = (o0 - 512) >> 6;   // 0,2,4,6 ; heads h0, h0+1
    // k2_ws: per (bh,ktile) 512 chunks [kh][ti][f][quad][col];
    // chunk = K[key=(2kh+ti)*16+col][d = (f*4+quad)*8 .. +8]
#pragma unroll
    for (int it = 0; it < 8; ++it) {
      const int ci = it * 256 + tid;              // 0..2047
      const int hh = ci >> 10, T = (ci >> 9) & 1, inner = ci & 511;
      const int ccol = inner & 15, cq = (inner >> 4) & 3;
      const int f = (inner >> 6) & 1, ti = (inner >> 7) & 1, kh2 = (inner >> 8) & 1;
      const int gmb = m0 + T * 64;
      const int bi = gmb / NSP, ktile = (gmb - bi * NSP) >> 6;
      const int m_l = T * 64 + (2 * kh2 + ti) * 16 + ccol;
      const int er0 = hh * 64 + (f * 4 + cq) * 8;
      short8 v; bf16* vp = (bf16*)&v;
#pragma unroll
      for (int j = 0; j < 8; ++j) vp[j] = ep[(er0 + j) * 132 + m_l];
      *(short8*)(k2_ws +
          (((size_t)(bi * 8 + h0 + hh) * 25 + ktile) * 512 + inner) * 8) = v;
    }
    // kt2_ws: per (bh,ktile) 512 chunks [kh][dt][quad][col];
    // chunk = kT[d=dt*16+col][packed keys kh*32+quad*4+{0..3}, +16+{0..3}]
#pragma unroll
    for (int it = 0; it < 8; ++it) {
      const int ci = it * 256 + tid;
      const int hh = ci >> 10, T = (ci >> 9) & 1, inner = ci & 511;
      const int ccol = inner & 15, cq = (inner >> 4) & 3;
      const int dt = (inner >> 6) & 3, kh2 = (inner >> 8) & 1;
      const int gmb = m0 + T * 64;
      const int bi = gmb / NSP, ktile = (gmb - bi * NSP) >> 6;
      const bf16* eprow =
          ep + (hh * 64 + dt * 16 + ccol) * 132 + T * 64 + kh2 * 32 + cq * 4;
      short8 v;
      ((bfx4*)&v)[0] = *(const bfx4*)(eprow);
      ((bfx4*)&v)[1] = *(const bfx4*)(eprow + 16);
      *(short8*)(kt2_ws +
          (((size_t)(bi * 8 + h0 + hh) * 25 + ktile) * 512 + inner) * 8) = v;
    }
  }
}

// ---------------------------------------------------------------------------
// attn: R10 structure (LDS-free K-loop, 4 waves: qg=wave&1 32 qcols,
// kh=wave>>1 32 keys; XCD-swizzled flat grid 800; register double-buffer)
// + sched_barrier(0) after each LOADF so the prefetch loads cannot be sunk
// past the MFMA cluster (fixes VGPR=60 degenerate pipeline). No setprio.
// ---------------------------------------------------------------------------

#define LOADF(KF, KTF, KT)                                                    \
  {                                                                           \
    const bf16* kc_  = k2b  + (KT) * 4096;                                    \
    const bf16* kc2_ = kt2b + (KT) * 4096;                                    \
    _Pragma("unroll")                                                         \
    for (int ti = 0; ti < 2; ++ti)                                            \
      _Pragma("unroll")                                                       \
      for (int f = 0; f < 2; ++f)                                             \
        KF[ti][f] =                                                           \
            *(const short8*)(kc_ + (((kh * 2 + ti) * 2 + f) * 64 + lane) * 8);\
    _Pragma("unroll")                                                         \
    for (int dt = 0; dt < 4; ++dt)                                            \
      KTF[dt] = *(const short8*)(kc2_ + ((kh * 4 + dt) * 64 + lane) * 8);     \
  }

#define COMPUTEF(KF, KTF)                                                     \
  {                                                                           \
    f32x4 s[2][2];                                                            \
    _Pragma("unroll")                                                         \
    for (int ti = 0; ti < 2; ++ti)                                            \
      _Pragma("unroll")                                                       \
      for (int ct = 0; ct < 2; ++ct) {                                        \
        f32x4 t = {0.f, 0.f, 0.f, 0.f};                                       \
        t = mfma32(KF[ti][0], qb[ct][0], t);                                  \
        t = mfma32(KF[ti][1], qb[ct][1], t);                                  \
        s[ti][ct] = t;                                                        \
      }                                                                       \
    bfx4 p4[2][2];                                                            \
    _Pragma("unroll")                                                         \
    for (int ti = 0; ti < 2; ++ti)                                            \
      _Pragma("unroll")                                                       \
      for (int ct = 0; ct < 2; ++ct) {                                        \
        _Pragma("unroll")                                                     \
        for (int r = 0; r < 4; ++r) s[ti][ct][r] = __expf(s[ti][ct][r]);      \
        l_part[ct] +=                                                         \
            s[ti][ct][0] + s[ti][ct][1] + s[ti][ct][2] + s[ti][ct][3];        \
        bf16* pp = (bf16*)&p4[ti][ct];                                        \
        _Pragma("unroll")                                                     \
        for (int r = 0; r < 4; ++r) pp[r] = __float2bfloat16(s[ti][ct][r]);   \
      }                                                                       \
    _Pragma("unroll")                                                         \
    for (int dt = 0; dt < 4; ++dt) {                                          \
      bfx4 alo = __builtin_shufflevector(KTF[dt], KTF[dt], 0, 1, 2, 3);       \
      bfx4 ahi = __builtin_shufflevector(KTF[dt], KTF[dt], 4, 5, 6, 7);       \
      _Pragma("unroll")                                                       \
      for (int ct = 0; ct < 2; ++ct) {                                        \
        oacc[dt][ct] = mfma_k16(alo, p4[0][ct], oacc[dt][ct]);                \
        oacc[dt][ct] = mfma_k16(ahi, p4[1][ct], oacc[dt][ct]);                \
      }                                                                       \
    }                                                                         \
  }

extern "C" __global__ __launch_bounds__(256)
void attn_kernel(const bf16* __restrict__ q_ws, const bf16* __restrict__ k2_ws,
                 const bf16* __restrict__ kt2_ws, float* __restrict__ out)
{
  __shared__ float red[2][64][36];

  // XCD swizzle: flat id; id%8 selects XCD (round-robin heuristic) == bh%8,
  // so all 25 qt-blocks of a bh share one XCD's L2. Bijective on 0..799.
  const int id = blockIdx.x;
  const int xr = id & 7, inner = id >> 3;      // inner 0..99
  const int qt = inner % 25;
  const int bh = (inner / 25) * 8 + xr;        // 0..31
  const int b = bh >> 3, h = bh & 7;
  const int tid  = threadIdx.x;
  const int wave = tid >> 6;
  const int lane = tid & 63;
  const int col  = lane & 15;
  const int quad = lane >> 4;
  const int qg = wave & 1, kh = wave >> 1;

  // loop-invariant Q B-fragments (natural layout, one-time strided gather)
  short8 qb[2][2];
#pragma unroll
  for (int ct = 0; ct < 2; ++ct) {
    const bf16* qp =
        q_ws + ((size_t)bh * NSP + qt * 64 + (qg * 2 + ct) * 16 + col) * 64;
    qb[ct][0] = *(const short8*)(qp + quad * 8);
    qb[ct][1] = *(const short8*)(qp + 32 + quad * 8);
  }

  f32x4 oacc[4][2];
#pragma unroll
  for (int i = 0; i < 4; ++i)
#pragma unroll
    for (int j = 0; j < 2; ++j) oacc[i][j] = {0.f, 0.f, 0.f, 0.f};
  float l_part[2] = {0.f, 0.f};

  const bf16* k2b  = k2_ws  + (size_t)bh * 25 * 4096;
  const bf16* kt2b = kt2_ws + (size_t)bh * 25 * 4096;

  // register double-buffer: prefetch kt+1 while computing kt. The
  // sched_barrier(0) after each LOADF pins the loads' ISSUE before the
  // following MFMA cluster (scheduler may not sink them); the compiler's
  // auto-waitcnt still guards the consuming MFMAs.
  short8 kfA[2][2], ktfA[4], kfB[2][2], ktfB[4];
  LOADF(kfA, ktfA, 0)
#pragma unroll 1
  for (int i = 0; i < 12; ++i) {
    LOADF(kfB, ktfB, 2 * i + 1)
    __builtin_amdgcn_sched_barrier(0);
    COMPUTEF(kfA, ktfA)
    LOADF(kfA, ktfA, 2 * i + 2)
    __builtin_amdgcn_sched_barrier(0);
    COMPUTEF(kfB, ktfB)
  }
  COMPUTEF(kfA, ktfA)

  // reduce l over quads (this wave's 32 keys)
#pragma unroll
  for (int ct = 0; ct < 2; ++ct) {
    l_part[ct] += __shfl_xor(l_part[ct], 16, 64);
    l_part[ct] += __shfl_xor(l_part[ct], 32, 64);
  }

  // cross-wave (kh) reduce via LDS
  if (wave >= 2) {
    float* dst = &red[wave - 2][lane][0];
#pragma unroll
    for (int dt = 0; dt < 4; ++dt)
#pragma unroll
      for (int ct = 0; ct < 2; ++ct)
        *(f32x4*)(dst + (dt * 2 + ct) * 4) = oacc[dt][ct];
    dst[32] = l_part[0]; dst[33] = l_part[1];
  }
  __syncthreads();
  if (wave < 2) {
    const float* srcr = &red[wave][lane][0];
#pragma unroll
    for (int dt = 0; dt < 4; ++dt)
#pragma unroll
      for (int ct = 0; ct < 2; ++ct)
        oacc[dt][ct] += *(const f32x4*)(srcr + (dt * 2 + ct) * 4);
    const float inv0 = 1.f / (l_part[0] + srcr[32]);
    const float inv1 = 1.f / (l_part[1] + srcr[33]);
#pragma unroll
    for (int ct = 0; ct < 2; ++ct) {
      const float inv = ct ? inv1 : inv0;
      const int qrow = qt * 64 + (qg * 2 + ct) * 16 + col;
      float* ob = out + ((size_t)b * NSP + qrow) * CDIM + h * 64;
#pragma unroll
      for (int dt = 0; dt < 4; ++dt) {
        float4 v;
        v.x = oacc[dt][ct][0] * inv; v.y = oacc[dt][ct][1] * inv;
        v.z = oacc[dt][ct][2] * inv; v.w = oacc[dt][ct][3] * inv;
        *(float4*)(ob + dt * 16 + quad * 4) = v;
      }
    }
  }
}

extern "C" void kernel_launch(void* const* d_in, const int* in_sizes, int n_in,
                              void* d_out, int out_size, void* d_ws, size_t ws_size,
                              hipStream_t stream) {
  const float* x     = (const float*)d_in[0];
  const float* sin_t = (const float*)d_in[1];
  const float* cos_t = (const float*)d_in[2];
  const float* w_qkv = (const float*)d_in[3];
  const float* b_qkv = (const float*)d_in[4];
  float* out = (float*)d_out;

  const size_t QK = (size_t)32 * NSP * DH;
  bf16* q_ws   = (bf16*)d_ws;
  bf16* k2_ws  = q_ws + QK;
  bf16* kt2_ws = k2_ws + QK;
  bf16* x_bf   = kt2_ws + QK;
  bf16* w_bf   = x_bf + (size_t)6400 * CDIM;
  float* sinT  = (float*)(w_bf + (size_t)1024 * CDIM);
  float* cosT  = sinT + (size_t)DH * NSP;

  cvt_kernel<<<1906, 256, 0, stream>>>(x, w_qkv, sin_t, cos_t, x_bf, w_bf, sinT, cosT);

  dim3 gproj(50, 8);
  proj_kernel<<<gproj, 256, 0, stream>>>(x_bf, w_bf, b_qkv, sinT, cosT,
                                         q_ws, k2_ws, kt2_ws);

  attn_kernel<<<800, 256, 0, stream>>>(q_ws, k2_ws, kt2_ws, out);
}